// Round 1
// baseline (1025.637 us; speedup 1.0000x reference)
//
#include <hip/hip_runtime.h>
#include <stdint.h>

#define Bn 256
#define Tn 127
#define Kn 128
#define Hn 256

typedef float f32x4 __attribute__((ext_vector_type(4)));
typedef short s16x8 __attribute__((ext_vector_type(8)));

__device__ __forceinline__ unsigned short f2bf(float f){
  union { float f; unsigned u; } v; v.f = f;
  unsigned r = v.u + 0x7FFFu + ((v.u >> 16) & 1u);
  return (unsigned short)(r >> 16);
}
__device__ __forceinline__ float bf2f(unsigned short b){
  union { unsigned u; float f; } v; v.u = ((unsigned)b) << 16; return v.f;
}
__device__ __forceinline__ s16x8 packf8(f32x4 a, f32x4 b){
  s16x8 r;
#pragma unroll
  for (int j=0;j<4;j++) r[j] = (short)f2bf(a[j]);
#pragma unroll
  for (int j=0;j<4;j++) r[4+j] = (short)f2bf(b[j]);
  return r;
}
__device__ __forceinline__ float sigf(float x){ return 1.f/(1.f+__expf(-x)); }
__device__ __forceinline__ float tanh_fast(float x){
  float ax = fabsf(x);
  float e = __expf(-2.f*ax);
  float t = (1.f - e)/(1.f + e);
  return x < 0.f ? -t : t;
}

// ---------------- Phase 0: alpha = softmax(x_score), weight = alpha*input -----
__global__ __launch_bounds__(128) void phase0_kernel(
    const float* __restrict__ in, const float* __restrict__ fc_w,
    float* __restrict__ out)
{
  const int b = blockIdx.x;
  const int k = threadIdx.x;            // 0..127
  __shared__ float wx[Tn];
  __shared__ float red[4];
  if (k < Tn) wx[k] = fc_w[2*Hn + k];   // W_x = fc_w[512:639]
  __syncthreads();

  const float* ib = in + (size_t)b*Tn*Kn;
  float acc = 0.f;
  for (int t=0;t<Tn;t++) acc += ib[t*Kn + k] * wx[t];
  // softmax over 128 (shift by fc_b and per-step scalar cancels)
  float m = acc;
#pragma unroll
  for (int o=32;o>0;o>>=1) m = fmaxf(m, __shfl_xor(m, o));
  const int wave = k >> 6;
  if ((k & 63) == 0) red[wave] = m;
  __syncthreads();
  m = fmaxf(red[0], red[1]);
  float e = __expf(acc - m);
  float ssum = e;
#pragma unroll
  for (int o=32;o>0;o>>=1) ssum += __shfl_xor(ssum, o);
  if ((k & 63) == 0) red[2+wave] = ssum;
  __syncthreads();
  const float alpha = e / (red[2] + red[3]);

  float* ob = out + (size_t)b*Tn*Kn;
  for (int t=0;t<Tn;t++)
    ob[t*Kn + k] = alpha * ib[t*Kn + k];
}

// ---------------- Scan: 16 batch-groups x 4 N-slices, W in registers ---------
// WG = 512 thr (8 waves). Wave w handles units u in [s*64+w*8, +8), i.e. 32
// gate-cols as two 16x16 MFMA tiles: tile0 = [i(8) | g(8)], tile1 = [f(8) | o(8)].
__global__ __launch_bounds__(512, 2) void scan_kernel(
    const float* __restrict__ W_ih, const float* __restrict__ W_hh,
    const float* __restrict__ b_ih, const float* __restrict__ b_hh,
    float* __restrict__ out, unsigned* __restrict__ bar)
{
  const int bid  = blockIdx.x;
  const int s    = bid >> 4;          // slice 0..3
  const int g    = bid & 15;          // batch group 0..15 (members share XCD: bid%8==g%8)
  const int b0   = g * 16;
  const int tid  = threadIdx.x;
  const int w    = tid >> 6;          // wave 0..7
  const int lane = tid & 63;
  const int c    = lane & 15;         // MFMA col / A-row lane id
  const int quad = lane >> 4;         // k-quad
  const int u    = s*64 + w*8 + (c & 7);       // global hidden unit for this lane
  const int row0 = (c < 8) ? u       : 512 + u; // tile0: i | g
  const int row1 = (c < 8) ? 256 + u : 768 + u; // tile1: f | o

  __shared__ __align__(16) unsigned short hhi[16*264]; // padded stride 264 (2-way free)
  __shared__ __align__(16) unsigned short hlo[16*264];
  __shared__ __align__(16) float hout[16*66];

  // --- persistent B fragments (bf16) in registers ---
  s16x8 whh0[8], whh1[8], wih0[4], wih1[4];
#pragma unroll
  for (int kb=0; kb<8; kb++){
    const float* p0 = W_hh + (size_t)row0*Hn + kb*32 + quad*8;
    const float* p1 = W_hh + (size_t)row1*Hn + kb*32 + quad*8;
    whh0[kb] = packf8(*(const f32x4*)p0, *(const f32x4*)(p0+4));
    whh1[kb] = packf8(*(const f32x4*)p1, *(const f32x4*)(p1+4));
  }
#pragma unroll
  for (int kb=0; kb<4; kb++){
    const float* p0 = W_ih + (size_t)row0*Kn + kb*32 + quad*8;
    const float* p1 = W_ih + (size_t)row1*Kn + kb*32 + quad*8;
    wih0[kb] = packf8(*(const f32x4*)p0, *(const f32x4*)(p0+4));
    wih1[kb] = packf8(*(const f32x4*)p1, *(const f32x4*)(p1+4));
  }
  const float bias0 = b_ih[row0] + b_hh[row0];
  const float bias1 = b_ih[row1] + b_hh[row1];

  // zero h LDS (t=0 state)
  {
    s16x8 z = {0,0,0,0,0,0,0,0};
    for (int i=tid; i<528; i+=512){ ((s16x8*)hhi)[i] = z; ((s16x8*)hlo)[i] = z; }
  }
  __syncthreads();

  float cst[4] = {0.f,0.f,0.f,0.f};
  const size_t enc_base = (size_t)Bn*Tn*Kn;

  for (int t=0; t<Tn; t++){
    if (t > 0){
      // stage h_{t-1} (fp32, from encode output rows) -> bf16 hi/lo in LDS
      const int m  = tid >> 5;
      const int k0 = (tid & 31) * 8;
      const float* hp = out + enc_base + ((size_t)(b0+m)*Tn + (t-1))*Hn + k0;
      f32x4 ha = *(const f32x4*)hp;
      f32x4 hb = *(const f32x4*)(hp+4);
      s16x8 vh, vl;
#pragma unroll
      for (int j=0;j<4;j++){
        unsigned short hi = f2bf(ha[j]);
        vh[j]   = (short)hi;
        vl[j]   = (short)f2bf(ha[j] - bf2f(hi));
      }
#pragma unroll
      for (int j=0;j<4;j++){
        unsigned short hi = f2bf(hb[j]);
        vh[4+j] = (short)hi;
        vl[4+j] = (short)f2bf(hb[j] - bf2f(hi));
      }
      *(s16x8*)&hhi[m*264 + k0] = vh;
      *(s16x8*)&hlo[m*264 + k0] = vl;
    }
    __syncthreads();

    f32x4 acc0 = {0.f,0.f,0.f,0.f}, acc1 = {0.f,0.f,0.f,0.f};
#pragma unroll
    for (int kb=0; kb<8; kb++){
      s16x8 ah = *(const s16x8*)&hhi[c*264 + kb*32 + quad*8];
      s16x8 al = *(const s16x8*)&hlo[c*264 + kb*32 + quad*8];
      acc0 = __builtin_amdgcn_mfma_f32_16x16x32_bf16(ah, whh0[kb], acc0, 0,0,0);
      acc1 = __builtin_amdgcn_mfma_f32_16x16x32_bf16(ah, whh1[kb], acc1, 0,0,0);
      acc0 = __builtin_amdgcn_mfma_f32_16x16x32_bf16(al, whh0[kb], acc0, 0,0,0);
      acc1 = __builtin_amdgcn_mfma_f32_16x16x32_bf16(al, whh1[kb], acc1, 0,0,0);
    }
    {
      // x part: read weight output (already alpha-scaled), cvt to bf16 A-frags
      const float* xp = out + ((size_t)(b0 + c)*Tn + t)*Kn + quad*8;
#pragma unroll
      for (int kb=0; kb<4; kb++){
        f32x4 xa  = *(const f32x4*)(xp + kb*32);
        f32x4 xb2 = *(const f32x4*)(xp + kb*32 + 4);
        s16x8 ax = packf8(xa, xb2);
        acc0 = __builtin_amdgcn_mfma_f32_16x16x32_bf16(ax, wih0[kb], acc0, 0,0,0);
        acc1 = __builtin_amdgcn_mfma_f32_16x16x32_bf16(ax, wih1[kb], acc1, 0,0,0);
      }
    }
    // epilogue: lanes c<8 own (i,f); partners at lane^8 own (g,o)
#pragma unroll
    for (int r=0; r<4; r++){
      float v0 = acc0[r] + bias0;               // i (c<8) | g (c>=8)
      float v1 = acc1[r] + bias1;               // f (c<8) | o (c>=8)
      float a0 = (c < 8) ? sigf(v0) : tanh_fast(v0);
      float a1 = sigf(v1);
      float pg = __shfl_xor(a0, 8);             // lanes<8: tanh(g)
      float po = __shfl_xor(a1, 8);             // lanes<8: sig(o)
      if (c < 8){
        cst[r] = a1*cst[r] + a0*pg;             // sig(f)*c + sig(i)*tanh(g)
        hout[(quad*4 + r)*66 + w*8 + c] = po * tanh_fast(cst[r]);
      }
    }
    __syncthreads();
    {
      // cooperative coalesced store of this WG's h slice (16 batches x 64 units)
      const int i  = tid * 2;
      const int m  = i >> 6;
      const int uu = i & 63;
      const float2 hv = *(const float2*)&hout[m*66 + uu];
      float* op = out + enc_base + ((size_t)(b0+m)*Tn + t)*Hn + s*64 + uu;
      op[0] = hv.x; op[1] = hv.y;
    }
    if (t < Tn-1){
      __syncthreads();                          // all waves' stores drained to L2
      if (tid == 0){
        __threadfence();                        // release: WB L2 -> device visible
        __hip_atomic_fetch_add(&bar[g], 1u, __ATOMIC_RELEASE, __HIP_MEMORY_SCOPE_AGENT);
        const unsigned tgt = 4u * (unsigned)(t+1);
        while (__hip_atomic_load(&bar[g], __ATOMIC_RELAXED, __HIP_MEMORY_SCOPE_AGENT) < tgt){
          __builtin_amdgcn_s_sleep(1);
        }
        __threadfence();                        // acquire: invalidate L1/L2
      }
      __syncthreads();
    }
  }
}

extern "C" void kernel_launch(void* const* d_in, const int* in_sizes, int n_in,
                              void* d_out, int out_size, void* d_ws, size_t ws_size,
                              hipStream_t stream) {
  const float* input = (const float*)d_in[0];
  const float* W_ih  = (const float*)d_in[1];
  const float* W_hh  = (const float*)d_in[2];
  const float* b_ih  = (const float*)d_in[3];
  const float* b_hh  = (const float*)d_in[4];
  const float* fc_w  = (const float*)d_in[5];
  float* out = (float*)d_out;
  unsigned* bar = (unsigned*)d_ws;   // 16 group barrier counters

  hipMemsetAsync(bar, 0, 16*sizeof(unsigned), stream);
  phase0_kernel<<<Bn, 128, 0, stream>>>(input, fc_w, out);
  scan_kernel<<<64, 512, 0, stream>>>(W_ih, W_hh, b_ih, b_hh, out, bar);
}

// Round 2
// 728.221 us; speedup vs baseline: 1.4084x; 1.4084x over previous
//
#include <hip/hip_runtime.h>
#include <stdint.h>

#define Bn 256
#define Tn 127
#define Kn 128
#define Hn 256

typedef float f32x4 __attribute__((ext_vector_type(4)));
typedef short s16x8 __attribute__((ext_vector_type(8)));

__device__ __forceinline__ unsigned short f2bf(float f){
  union { float f; unsigned u; } v; v.f = f;
  unsigned r = v.u + 0x7FFFu + ((v.u >> 16) & 1u);
  return (unsigned short)(r >> 16);
}
__device__ __forceinline__ float bf2f(unsigned short b){
  union { unsigned u; float f; } v; v.u = ((unsigned)b) << 16; return v.f;
}
__device__ __forceinline__ s16x8 packf8(f32x4 a, f32x4 b){
  s16x8 r;
#pragma unroll
  for (int j=0;j<4;j++) r[j] = (short)f2bf(a[j]);
#pragma unroll
  for (int j=0;j<4;j++) r[4+j] = (short)f2bf(b[j]);
  return r;
}
__device__ __forceinline__ float sigf(float x){ return 1.f/(1.f+__expf(-x)); }
__device__ __forceinline__ float tanh_fast(float x){
  float ax = fabsf(x);
  float e = __expf(-2.f*ax);
  float t = (1.f - e)/(1.f + e);
  return x < 0.f ? -t : t;
}

// ---------------- Phase 0: alpha = softmax(x_score), weight = alpha*input -----
__global__ __launch_bounds__(128) void phase0_kernel(
    const float* __restrict__ in, const float* __restrict__ fc_w,
    float* __restrict__ out)
{
  const int b = blockIdx.x;
  const int k = threadIdx.x;            // 0..127
  __shared__ float wx[Tn];
  __shared__ float red[4];
  if (k < Tn) wx[k] = fc_w[2*Hn + k];   // W_x = fc_w[512:639]
  __syncthreads();

  const float* ib = in + (size_t)b*Tn*Kn;
  float acc = 0.f;
#pragma unroll 8
  for (int t=0;t<Tn;t++) acc += ib[t*Kn + k] * wx[t];
  float m = acc;
#pragma unroll
  for (int o=32;o>0;o>>=1) m = fmaxf(m, __shfl_xor(m, o));
  const int wave = k >> 6;
  if ((k & 63) == 0) red[wave] = m;
  __syncthreads();
  m = fmaxf(red[0], red[1]);
  float e = __expf(acc - m);
  float ssum = e;
#pragma unroll
  for (int o=32;o>0;o>>=1) ssum += __shfl_xor(ssum, o);
  if ((k & 63) == 0) red[2+wave] = ssum;
  __syncthreads();
  const float alpha = e / (red[2] + red[3]);

  float* ob = out + (size_t)b*Tn*Kn;
#pragma unroll 4
  for (int t=0;t<Tn;t++)
    ob[t*Kn + k] = alpha * ib[t*Kn + k];
}

// ---------------- Scan: 16 batch-groups x 4 N-slices, W in registers ---------
// Exchange of h between the 4 slice-WGs of a group goes through the encode
// output rows (t-indexed, so no WAR race) using agent-scope RELAXED atomics:
// stores are write-through to the device coherence point (acked before the
// signal add issues, via the vmcnt(0) drain inside __syncthreads), loads
// bypass stale L1/L2. NO __threadfence -> no L2-wide wb/inv per step.
__global__ __launch_bounds__(512, 2) void scan_kernel(
    const float* __restrict__ W_ih, const float* __restrict__ W_hh,
    const float* __restrict__ b_ih, const float* __restrict__ b_hh,
    float* __restrict__ out, unsigned* __restrict__ bar)
{
  const int bid  = blockIdx.x;
  const int s    = bid >> 4;          // slice 0..3
  const int g    = bid & 15;          // batch group 0..15
  const int b0   = g * 16;
  const int tid  = threadIdx.x;
  const int w    = tid >> 6;          // wave 0..7
  const int lane = tid & 63;
  const int c    = lane & 15;         // MFMA col (gate unit) / A-row (batch)
  const int quad = lane >> 4;         // k-quad
  const int u    = s*64 + w*8 + (c & 7);
  const int row0 = (c < 8) ? u       : 512 + u; // tile0: i | g
  const int row1 = (c < 8) ? 256 + u : 768 + u; // tile1: f | o

  // stride 272 shorts = 136 dw; frag read bank = (8c+4q) mod 32 -> 4-way (was 8)
  __shared__ __align__(16) unsigned short hhi[16*272];
  __shared__ __align__(16) unsigned short hlo[16*272];
  __shared__ __align__(16) float hout[16*66];

  // --- persistent B fragments (bf16) in registers ---
  s16x8 whh0[8], whh1[8], wih0[4], wih1[4];
#pragma unroll
  for (int kb=0; kb<8; kb++){
    const float* p0 = W_hh + (size_t)row0*Hn + kb*32 + quad*8;
    const float* p1 = W_hh + (size_t)row1*Hn + kb*32 + quad*8;
    whh0[kb] = packf8(*(const f32x4*)p0, *(const f32x4*)(p0+4));
    whh1[kb] = packf8(*(const f32x4*)p1, *(const f32x4*)(p1+4));
  }
#pragma unroll
  for (int kb=0; kb<4; kb++){
    const float* p0 = W_ih + (size_t)row0*Kn + kb*32 + quad*8;
    const float* p1 = W_ih + (size_t)row1*Kn + kb*32 + quad*8;
    wih0[kb] = packf8(*(const f32x4*)p0, *(const f32x4*)(p0+4));
    wih1[kb] = packf8(*(const f32x4*)p1, *(const f32x4*)(p1+4));
  }
  const float bias0 = b_ih[row0] + b_hh[row0];
  const float bias1 = b_ih[row1] + b_hh[row1];

  float cst[4] = {0.f,0.f,0.f,0.f};
  const size_t enc_base = (size_t)Bn*Tn*Kn;
  unsigned* mybar = &bar[g*32];       // 128B apart per group

  for (int t=0; t<Tn; t++){
    // ---- x prefetch: independent of the h exchange; issue before the wait
    const float* xp = out + ((size_t)(b0 + c)*Tn + t)*Kn + quad*8;
    f32x4 xv[8];
#pragma unroll
    for (int kb=0; kb<4; kb++){
      xv[2*kb]   = *(const f32x4*)(xp + kb*32);
      xv[2*kb+1] = *(const f32x4*)(xp + kb*32 + 4);
    }

    if (t > 0){
      if (tid == 0){
        const unsigned tgt = 4u * (unsigned)t;
        while (__hip_atomic_load(mybar, __ATOMIC_RELAXED, __HIP_MEMORY_SCOPE_AGENT) < tgt)
          __builtin_amdgcn_s_sleep(1);
      }
      __syncthreads();
      // ---- stage h_{t-1}: agent-scope loads (bypass stale caches) -> hi/lo LDS
      const int m  = tid >> 5;
      const int k0 = (tid & 31) * 8;
      const unsigned long long* hp = (const unsigned long long*)
          (out + enc_base + ((size_t)(b0+m)*Tn + (t-1))*Hn + k0);
      union { unsigned long long q; float f[2]; } a0, a1, a2, a3;
      a0.q = __hip_atomic_load(hp+0, __ATOMIC_RELAXED, __HIP_MEMORY_SCOPE_AGENT);
      a1.q = __hip_atomic_load(hp+1, __ATOMIC_RELAXED, __HIP_MEMORY_SCOPE_AGENT);
      a2.q = __hip_atomic_load(hp+2, __ATOMIC_RELAXED, __HIP_MEMORY_SCOPE_AGENT);
      a3.q = __hip_atomic_load(hp+3, __ATOMIC_RELAXED, __HIP_MEMORY_SCOPE_AGENT);
      float hv[8] = {a0.f[0],a0.f[1],a1.f[0],a1.f[1],a2.f[0],a2.f[1],a3.f[0],a3.f[1]};
      s16x8 vh, vl;
#pragma unroll
      for (int j=0;j<8;j++){
        unsigned short hi = f2bf(hv[j]);
        vh[j] = (short)hi;
        vl[j] = (short)f2bf(hv[j] - bf2f(hi));
      }
      *(s16x8*)&hhi[m*272 + k0] = vh;
      *(s16x8*)&hlo[m*272 + k0] = vl;
      __syncthreads();
    }

    // ---- MFMA: separate acc chains (x / hi / lo) to cut dependent latency
    f32x4 acc0 = {0.f,0.f,0.f,0.f}, acc1 = {0.f,0.f,0.f,0.f};
    f32x4 a0h = {0.f,0.f,0.f,0.f}, a1h = {0.f,0.f,0.f,0.f};
    f32x4 a0l = {0.f,0.f,0.f,0.f}, a1l = {0.f,0.f,0.f,0.f};
#pragma unroll
    for (int kb=0; kb<4; kb++){
      s16x8 ax = packf8(xv[2*kb], xv[2*kb+1]);
      acc0 = __builtin_amdgcn_mfma_f32_16x16x32_bf16(ax, wih0[kb], acc0, 0,0,0);
      acc1 = __builtin_amdgcn_mfma_f32_16x16x32_bf16(ax, wih1[kb], acc1, 0,0,0);
    }
    if (t > 0){
#pragma unroll
      for (int kb=0; kb<8; kb++){
        s16x8 ah = *(const s16x8*)&hhi[c*272 + kb*32 + quad*8];
        s16x8 al = *(const s16x8*)&hlo[c*272 + kb*32 + quad*8];
        a0h = __builtin_amdgcn_mfma_f32_16x16x32_bf16(ah, whh0[kb], a0h, 0,0,0);
        a1h = __builtin_amdgcn_mfma_f32_16x16x32_bf16(ah, whh1[kb], a1h, 0,0,0);
        a0l = __builtin_amdgcn_mfma_f32_16x16x32_bf16(al, whh0[kb], a0l, 0,0,0);
        a1l = __builtin_amdgcn_mfma_f32_16x16x32_bf16(al, whh1[kb], a1l, 0,0,0);
      }
#pragma unroll
      for (int r=0;r<4;r++){ acc0[r] += a0h[r] + a0l[r]; acc1[r] += a1h[r] + a1l[r]; }
    }

    // ---- epilogue: lanes c<8 own (i,f); partners at lane^8 own (g,o)
#pragma unroll
    for (int r=0; r<4; r++){
      float v0 = acc0[r] + bias0;               // i (c<8) | g (c>=8)
      float v1 = acc1[r] + bias1;               // f (c<8) | o (c>=8)
      float a0 = (c < 8) ? sigf(v0) : tanh_fast(v0);
      float a1 = sigf(v1);
      float pg = __shfl_xor(a0, 8);
      float po = __shfl_xor(a1, 8);
      if (c < 8){
        cst[r] = a1*cst[r] + a0*pg;
        hout[(quad*4 + r)*66 + w*8 + c] = po * tanh_fast(cst[r]);
      }
    }
    __syncthreads();

    // ---- cooperative h store: agent-scope write-through (16 batches x 64 u)
    {
      const int i  = tid * 2;
      const int m  = i >> 6;
      const int uu = i & 63;
      union { float f[2]; unsigned long long q; } uo;
      const float2 hv = *(const float2*)&hout[m*66 + uu];
      uo.f[0] = hv.x; uo.f[1] = hv.y;
      unsigned long long* op = (unsigned long long*)
          (out + enc_base + ((size_t)(b0+m)*Tn + t)*Hn + s*64 + uu);
      __hip_atomic_store(op, uo.q, __ATOMIC_RELAXED, __HIP_MEMORY_SCOPE_AGENT);
    }
    if (t < Tn-1){
      __syncthreads();   // vmcnt(0) drain: h stores acked at coherence point
      if (tid == 0)
        __hip_atomic_fetch_add(mybar, 1u, __ATOMIC_RELAXED, __HIP_MEMORY_SCOPE_AGENT);
    }
  }
}

extern "C" void kernel_launch(void* const* d_in, const int* in_sizes, int n_in,
                              void* d_out, int out_size, void* d_ws, size_t ws_size,
                              hipStream_t stream) {
  const float* input = (const float*)d_in[0];
  const float* W_ih  = (const float*)d_in[1];
  const float* W_hh  = (const float*)d_in[2];
  const float* b_ih  = (const float*)d_in[3];
  const float* b_hh  = (const float*)d_in[4];
  const float* fc_w  = (const float*)d_in[5];
  float* out = (float*)d_out;
  unsigned* bar = (unsigned*)d_ws;   // 16 groups x 32 uints (128B apart)

  hipMemsetAsync(bar, 0, 16*32*sizeof(unsigned), stream);
  phase0_kernel<<<Bn, 128, 0, stream>>>(input, fc_w, out);
  scan_kernel<<<64, 512, 0, stream>>>(W_ih, W_hh, b_ih, b_hh, out, bar);
}